// Round 2
// baseline (716.858 us; speedup 1.0000x reference)
//
#include <hip/hip_runtime.h>

#define THREADS 256
#define F_HID 10
#define F_OUT 19

// Packed weights in constant address space -> guaranteed s_load (scalar,
// K$-cached, broadcast). Layout (float offsets):
//   [0,40)    W1[4][10] row-major
//   [40,50)   b1[10]
//   [50,240)  W2[10][19] row-major
//   [240,259) b2[19]
__constant__ float c_pack[260];

__global__ __launch_bounds__(THREADS) void edge_mlp_kernel(
    const float* __restrict__ src,
    const float* __restrict__ dst,
    const float* __restrict__ ea,
    const float* __restrict__ u,      // [4096] = 16 KB, L1-resident gather
    const int*   __restrict__ batch,  // [E] int32
    float* __restrict__ out,          // [E,19]
    int n_edges)
{
    // Stage one block's output contiguously; flat float4 copy-out is coalesced.
    __shared__ float lds[THREADS * F_OUT]; // 19456 B -> 8 blocks/CU (LDS-wise)

    const int tid = threadIdx.x;
    const int e   = blockIdx.x * THREADS + tid;

    float o[F_OUT];
    if (e < n_edges) {
        const float x0 = src[e];
        const float x1 = dst[e];
        const float x2 = ea[e];
        const float x3 = u[batch[e]];

        #pragma unroll
        for (int k = 0; k < F_OUT; ++k) o[k] = c_pack[240 + k];

        #pragma unroll
        for (int j = 0; j < F_HID; ++j) {
            float a = c_pack[40 + j];                 // b1[j]
            a = fmaf(x0, c_pack[ 0 + j], a);          // W1[0][j]
            a = fmaf(x1, c_pack[10 + j], a);          // W1[1][j]
            a = fmaf(x2, c_pack[20 + j], a);          // W1[2][j]
            a = fmaf(x3, c_pack[30 + j], a);          // W1[3][j]
            a = fmaxf(a, 0.0f);                       // ReLU
            #pragma unroll
            for (int k = 0; k < F_OUT; ++k)
                o[k] = fmaf(a, c_pack[50 + j * F_OUT + k], o[k]); // W2[j][k]
        }
    } else {
        #pragma unroll
        for (int k = 0; k < F_OUT; ++k) o[k] = 0.0f;
    }

    // Inter-lane LDS stride = 19 dwords (odd) -> 2 lanes/bank = free (m136).
    #pragma unroll
    for (int k = 0; k < F_OUT; ++k) lds[tid * F_OUT + k] = o[k];
    __syncthreads();

    const int block_start = blockIdx.x * THREADS;
    const int base  = block_start * F_OUT;   // fits int (max ~152M)
    const int valid = n_edges - block_start;
    if (valid >= THREADS) {
        // 19456 B block region, 16B-aligned (19456 % 16 == 0): pure dwordx4.
        float4* __restrict__ outv = (float4*)(out + base);
        const float4* __restrict__ ldsv = (const float4*)lds;
        #pragma unroll
        for (int idx = tid; idx < (THREADS * F_OUT) / 4; idx += THREADS)
            outv[idx] = ldsv[idx];
    } else {
        const int nflt = valid * F_OUT;
        for (int idx = tid; idx < nflt; idx += THREADS)
            out[base + idx] = lds[idx];
    }
}

extern "C" void kernel_launch(void* const* d_in, const int* in_sizes, int n_in,
                              void* d_out, int out_size, void* d_ws, size_t ws_size,
                              hipStream_t stream) {
    const float* src   = (const float*)d_in[0];
    const float* dst   = (const float*)d_in[1];
    const float* ea    = (const float*)d_in[2];
    const float* u     = (const float*)d_in[3];
    const int*   batch = (const int*)  d_in[4];

    // Pack weights into __constant__ c_pack each call (capture-legal D2D async).
    void* sym = nullptr;
    (void)hipGetSymbolAddress(&sym, HIP_SYMBOL(c_pack));
    char* cp = (char*)sym;
    (void)hipMemcpyAsync(cp +   0, d_in[5], 40  * sizeof(float), hipMemcpyDeviceToDevice, stream); // W1
    (void)hipMemcpyAsync(cp + 160, d_in[6], 10  * sizeof(float), hipMemcpyDeviceToDevice, stream); // b1
    (void)hipMemcpyAsync(cp + 200, d_in[7], 190 * sizeof(float), hipMemcpyDeviceToDevice, stream); // W2
    (void)hipMemcpyAsync(cp + 960, d_in[8], 19  * sizeof(float), hipMemcpyDeviceToDevice, stream); // b2

    float* out = (float*)d_out;
    const int n = in_sizes[0];  // E
    const int blocks = (n + THREADS - 1) / THREADS;
    edge_mlp_kernel<<<blocks, THREADS, 0, stream>>>(src, dst, ea, u, batch, out, n);
}